// Round 8
// baseline (154.240 us; speedup 1.0000x reference)
//
#include <hip/hip_runtime.h>
#include <math.h>

#define BATCH 16
#define LEN   160000
#define NFFT  512
#define HOP   128
#define NT    1251      // 1 + (160000+512-512)/128
#define NF    257
#define PADC  256
#define TWO_PI 6.28318530717958647692f
// padded LDS index: +1 float per 32 -> breaks power-of-2 bank aliasing
#define P(i) ((i) + ((i) >> 5))
#define FBUF 528        // padded 512-float FFT region (P(511)=526 < 528)
#define GSTR 264        // staging row stride: 2 rows == FBUF exactly

__device__ __forceinline__ int reflect_idx(int j) {
    j = j < 0 ? -j : j;
    j = j >= LEN ? 2*LEN - 2 - j : j;
    return j;
}

__device__ __forceinline__ float hann(int n) {
    return 0.5f - 0.5f * __cosf(TWO_PI * (float)n * (1.0f / 512.0f));
}

// ---------- sorted-4-smallest tuple machinery (exact, branchless) ----------
struct T4 { float m0, m1, m2, m3; };   // ascending

__device__ __forceinline__ void ins(T4& a, float v) {
    const float x0 = fminf(a.m0, v);  const float c0 = fmaxf(a.m0, v);
    const float x1 = fminf(a.m1, c0); const float c1 = fmaxf(a.m1, c0);
    const float x2 = fminf(a.m2, c1); const float c2 = fmaxf(a.m2, c1);
    const float x3 = fminf(a.m3, c2);
    a.m0 = x0; a.m1 = x1; a.m2 = x2; a.m3 = x3;
}

__device__ __forceinline__ T4 merge4(const T4& a, const T4& b) {
    const float l0 = fminf(a.m0, b.m3);
    const float l1 = fminf(a.m1, b.m2);
    const float l2 = fminf(a.m2, b.m1);
    const float l3 = fminf(a.m3, b.m0);
    const float t0 = fminf(l0, l2), t2 = fmaxf(l0, l2);
    const float t1 = fminf(l1, l3), t3 = fmaxf(l1, l3);
    T4 r;
    r.m0 = fminf(t0, t1); r.m1 = fmaxf(t0, t1);
    r.m2 = fminf(t2, t3); r.m3 = fmaxf(t2, t3);
    return r;
}

__device__ __forceinline__ T4 sort4(float a, float b, float c, float d) {
    const float x0 = fminf(a, b), x1 = fmaxf(a, b);
    const float x2 = fminf(c, d), x3 = fmaxf(c, d);
    const float y0 = fminf(x0, x2), y2 = fmaxf(x0, x2);
    const float y1 = fminf(x1, x3), y3 = fmaxf(x1, x3);
    T4 r; r.m0 = y0; r.m1 = fminf(y1, y2); r.m2 = fmaxf(y1, y2); r.m3 = y3;
    return r;
}

// 8-point DFT in registers. y[m] = sum_r v[r] * exp(sign*2*pi*i*r*m/8).
__device__ __forceinline__ void dft8(float vr[8], float vi[8], float sign) {
    const float K = 0.70710678118654752f;
    float ar=vr[0]+vr[4], ai=vi[0]+vi[4];
    float br=vr[0]-vr[4], bi=vi[0]-vi[4];
    float cr=vr[2]+vr[6], ci=vi[2]+vi[6];
    float dr=vr[2]-vr[6], di=vi[2]-vi[6];
    float er=vr[1]+vr[5], ei=vi[1]+vi[5];
    float fr=vr[1]-vr[5], fi=vi[1]-vi[5];
    float gr=vr[3]+vr[7], gi=vi[3]+vi[7];
    float hr=vr[3]-vr[7], hi=vi[3]-vi[7];
    const float W4dr = -sign*di, W4di = sign*dr;
    const float W4hr = -sign*hi, W4hi = sign*hr;
    const float E0r=ar+cr, E0i=ai+ci, E2r=ar-cr, E2i=ai-ci;
    const float E1r=br+W4dr, E1i=bi+W4di, E3r=br-W4dr, E3i=bi-W4di;
    const float O0r=er+gr, O0i=ei+gi, O2r=er-gr, O2i=ei-gi;
    const float O1r=fr+W4hr, O1i=fi+W4hi, O3r=fr-W4hr, O3i=fi-W4hi;
    const float T1r = K*(O1r - sign*O1i), T1i = K*(O1i + sign*O1r);
    const float T2r = -sign*O2i,          T2i = sign*O2r;
    const float T3r = K*(-O3r - sign*O3i), T3i = K*(-O3i + sign*O3r);
    vr[0]=E0r+O0r; vi[0]=E0i+O0i;  vr[4]=E0r-O0r; vi[4]=E0i-O0i;
    vr[1]=E1r+T1r; vi[1]=E1i+T1i;  vr[5]=E1r-T1r; vi[5]=E1i-T1i;
    vr[2]=E2r+T2r; vi[2]=E2i+T2i;  vr[6]=E2r-T2r; vi[6]=E2i-T2i;
    vr[3]=E3r+T3r; vi[3]=E3i+T3i;  vr[7]=E3r-T3r; vi[7]=E3i-T3i;
}

// One Stockham radix-8 pass, IN PLACE, one wave = one FFT (j in 0..63).
// Safe without any barrier: all 8 ds_reads precede all 8 ds_writes in
// program order, and DS ops from one wave are processed in order.
template<int NS>
__device__ __forceinline__ void fft_pass(float* R, float* I, int j, float sign) {
    float vr[8], vi[8];
    #pragma unroll
    for (int r = 0; r < 8; ++r) { vr[r] = R[P(j + 64*r)]; vi[r] = I[P(j + 64*r)]; }
    const float th = sign * (TWO_PI / (8.0f * (float)NS)) * (float)(j & (NS - 1));
    float w1r, w1i; __sincosf(th, &w1i, &w1r);
    float wr = w1r, wi = w1i;
    #pragma unroll
    for (int r = 1; r < 8; ++r) {
        const float tr = vr[r]*wr - vi[r]*wi;
        vi[r] = vr[r]*wi + vi[r]*wr; vr[r] = tr;
        const float nwr = wr*w1r - wi*w1i;
        wi = wr*w1i + wi*w1r; wr = nwr;
    }
    dft8(vr, vi, sign);
    const int base = ((j / NS) * (8 * NS)) + (j & (NS - 1));
    #pragma unroll
    for (int r = 0; r < 8; ++r) { R[P(base + r*NS)] = vr[r]; I[P(base + r*NS)] = vi[r]; }
}

// K1: STFT of BOTH signals via one complex FFT per frame: z = enh + i*noi.
// 4 frames per block (one per wave), wave-autonomous in-place radix-8
// Stockham, ZERO __syncthreads.
__global__ __launch_bounds__(256, 4) void stft_kernel(const float* __restrict__ enh,
                                                      const float* __restrict__ noi,
                                                      float2* __restrict__ e_spec,
                                                      float*  __restrict__ n_mag) {
    __shared__ float Ar[4*FBUF], Ai[4*FBUF];
    const int tid = threadIdx.x;
    const int w = tid >> 6, j = tid & 63;
    const int tr_ = blockIdx.x * 4 + w;
    const bool live = tr_ < NT;
    const int t = live ? tr_ : NT - 1;
    const int b = blockIdx.y;
    float* ar = Ar + w*FBUF; float* ai = Ai + w*FBUF;

    // pass 0: global -> registers (windowed, reflect-padded), dft8, write A
    {
        const int sbase = t * HOP - PADC;
        const float* __restrict__ pe = enh + b * LEN;
        const float* __restrict__ pn = noi + b * LEN;
        float vr[8], vi[8];
        #pragma unroll
        for (int r = 0; r < 8; ++r) {
            const int n = j + 64*r;
            const int idx = reflect_idx(sbase + n);
            const float wd = hann(n);
            vr[r] = pe[idx] * wd;
            vi[r] = pn[idx] * wd;
        }
        dft8(vr, vi, -1.0f);
        #pragma unroll
        for (int r = 0; r < 8; ++r) { ar[P(8*j + r)] = vr[r]; ai[P(8*j + r)] = vi[r]; }
    }
    fft_pass<8> (ar, ai, j, -1.0f);
    fft_pass<64>(ar, ai, j, -1.0f);

    // extract rfft of both signals: X=(Z(k)+conj(Z(512-k)))/2, Y=(Z(k)-conj(Z(512-k)))/2i
    if (live) {
        const int obase = (b * NT + t) * NF;
        #pragma unroll
        for (int r = 0; r < 5; ++r) {
            const int kk = j + 64*r;
            if (kk > 256) break;
            if (r == 4 && j != 0) break;
            const float zr = ar[P(kk)], zi = ai[P(kk)];
            const int n2 = (512 - kk) & 511;
            const float yr = ar[P(n2)], yi = ai[P(n2)];
            const float er = 0.5f*(zr + yr), ei = 0.5f*(zi - yi);
            const float nr = 0.5f*(zi + yi), ni = 0.5f*(yr - zr);
            e_spec[obase + kk] = make_float2(er, ei);
            n_mag[obase + kk] = fmaxf(sqrtf(nr*nr + ni*ni), 1e-6f);
        }
    }
}

// K2: FULLY fused floor. Tile = 16 outputs (24 quantile rows incl. +/-4
// halo; 54-element time window in registers). Quantile = 4th-smallest of
// 31 via chunked selection. Freq-pool k=5 via LDS; time-pool k=9 sliding.
__global__ __launch_bounds__(256) void floor_kernel(const float* __restrict__ n_mag,
                                                    float* __restrict__ floor_) {
    __shared__ float q[24][GSTR];
    __shared__ float fq[24];
    const int tid = threadIdx.x;
    const int t0 = blockIdx.x * 16, b = blockIdx.y;
    const float* __restrict__ pb = n_mag + b * NT * NF;

    // ---- phase A: quantile rows k=0..23 (tq = t0-4+k) for f = tid ----
    {
        float wv[54];
        #pragma unroll
        for (int r = 0; r < 54; ++r) {
            int tr = t0 - 19 + r;
            tr = tr < 0 ? 0 : (tr > NT - 1 ? NT - 1 : tr);
            wv[r] = pb[tr * NF + tid];
        }
        T4 ch[6];
        #pragma unroll
        for (int c = 0; c < 6; ++c)
            ch[c] = merge4(sort4(wv[8*c],   wv[8*c+1], wv[8*c+2], wv[8*c+3]),
                           sort4(wv[8*c+4], wv[8*c+5], wv[8*c+6], wv[8*c+7]));
        #pragma unroll
        for (int k = 0; k < 24; ++k) {
            const int c0 = (k + 7) >> 3;      // full chunks c0, c0+1, c0+2
            T4 m = merge4(merge4(ch[c0], ch[c0+1]), ch[c0+2]);
            #pragma unroll
            for (int jj = k; jj < 8*c0; ++jj) ins(m, wv[jj]);        // head
            #pragma unroll
            for (int jj = 8*c0 + 24; jj < k + 31; ++jj) ins(m, wv[jj]); // tail
            q[k][tid] = m.m3;
        }
    }
    // f = 256 column: threads 0..23, one quantile row each (naive 31-insert)
    if (tid < 24) {
        const int k = tid;
        T4 m; m.m0 = m.m1 = m.m2 = m.m3 = 3.4e38f;
        for (int dt = -15; dt <= 15; ++dt) {
            int tt = t0 - 4 + k + dt;
            tt = tt < 0 ? 0 : (tt > NT - 1 ? NT - 1 : tt);
            ins(m, pb[tt * NF + 256]);
        }
        q[k][256] = m.m3;
    }
    __syncthreads();

    // ---- phase B: freq pool k=5 (zero-pad) into registers ----
    float fp[24];
    {
        const int f = tid;
        #pragma unroll
        for (int k = 0; k < 24; ++k) {
            float acc = 0.0f;
            #pragma unroll
            for (int df = -2; df <= 2; ++df) {
                const int ff = f + df;
                if (ff >= 0 && ff < NF) acc += q[k][ff];
            }
            fp[k] = acc * (1.0f / 5.0f);
        }
    }
    if (tid < 24) {   // f = 256 pooled rows -> fq
        const int k = tid;
        fq[k] = (q[k][254] + q[k][255] + q[k][256]) * (1.0f / 5.0f);
    }
    __syncthreads();

    // ---- phase C: zero out-of-range rows, time pool k=9 sliding, store ----
    {
        const int f = tid;
        #pragma unroll
        for (int k = 0; k < 24; ++k) {
            const int tq = t0 - 4 + k;
            fp[k] = (tq >= 0 && tq < NT) ? fp[k] : 0.0f;
        }
        float acc = 0.0f;
        #pragma unroll
        for (int k = 0; k < 9; ++k) acc += fp[k];
        #pragma unroll
        for (int to = 0; to < 16; ++to) {
            const int t = t0 + to;
            if (t < NT)
                floor_[(b * NT + t) * NF + f] = fmaxf(acc * (1.0f / 9.0f), 1e-6f);
            if (to < 15) acc += fp[to + 9] - fp[to];
        }
    }
    if (tid < 16) {   // f = 256 outputs
        const int to = tid;
        const int t = t0 + to;
        if (t < NT) {
            float acc = 0.0f;
            #pragma unroll
            for (int k = 0; k < 9; ++k) {
                const int tq = t0 - 4 + to + k;
                acc += (tq >= 0 && tq < NT) ? fq[to + k] : 0.0f;
            }
            floor_[(b * NT + t) * NF + 256] = fmaxf(acc * (1.0f / 9.0f), 1e-6f);
        }
    }
}

// K3: fused [mask + ISTFT + OLA]. Block = 384 threads (6 waves), owns
// output slots t_hi in [t0, t0+8) (1024 samples). Computes 12 frames
// t0-4..t0+7 (incl. 3-frame halo + 1 pad) as 6 packed IFFTs, one per
// wave, entirely in LDS (staging region doubles as the frame store,
// windowed in place after the FFT). One barrier, then OLA -> out.
__global__ __launch_bounds__(384) void istft_ola_kernel(const float2* __restrict__ g,
                                                        const float* __restrict__ floor_,
                                                        float* __restrict__ out) {
    __shared__ float gr[12*GSTR], gi[12*GSTR];   // 12 rows = 6 wave regions
    const int tid = threadIdx.x;
    const int w = tid >> 6, j = tid & 63;
    const int t0 = blockIdx.x * 8, b = blockIdx.y;
    const int ta = t0 - 4 + 2*w, tb = ta + 1;    // this wave's frame pair

    float* g0r = gr + (2*w) * GSTR;      float* g0i = gi + (2*w) * GSTR;
    float* g1r = gr + (2*w + 1) * GSTR;  float* g1i = gi + (2*w + 1) * GSTR;

    // mask phase (wave-local): fill this wave's 2 staging rows
    for (int e = j; e < 2 * NF; e += 64) {
        const int h = (e >= NF) ? 1 : 0;
        const int kk = e - h * NF;
        const int t = ta + h;
        float grv = 0.0f, giv = 0.0f;
        if (t >= 0 && t < NT) {
            const int idx = (b * NT + t) * NF + kk;
            const float fl = floor_[idx];
            const float2 e2 = g[idx];
            const float a = sqrtf(e2.x * e2.x + e2.y * e2.y);
            const float emag = fmaxf(a, 1e-6f);
            const float xarg = (emag - 1.5f * fl) / (0.15f * fl + 1e-6f);
            const float mask = 1.0f / (1.0f + __expf(-xarg));
            const float fm = 0.08f + 0.92f * (0.65f + 0.35f * mask);
            const float scale = emag * fm / fmaxf(a, 1e-12f);
            grv = e2.x * scale; giv = e2.y * scale;
        }
        gr[(2*w + h) * GSTR + kk] = grv;
        gi[(2*w + h) * GSTR + kk] = giv;
    }

    float* ar = g0r;   // FFT region = this wave's two staging rows (528 floats)
    float* ai = g0i;

    // pass 0: build packed C(n) = G1full + i*G2full from staging, dft8,
    // write back into the same region (all reads precede all writes).
    {
        float vr[8], vi[8];
        #pragma unroll
        for (int r = 0; r < 8; ++r) {
            const int n = j + 64*r;
            float cr, ci;
            if (n <= 256) {
                cr = g0r[n] - g1i[n];
                ci = g0i[n] + g1r[n];
            } else {
                const int m = 512 - n;
                cr = g0r[m] + g1i[m];
                ci = g1r[m] - g0i[m];
            }
            vr[r] = cr; vi[r] = ci;
        }
        dft8(vr, vi, 1.0f);
        #pragma unroll
        for (int r = 0; r < 8; ++r) { ar[P(8*j + r)] = vr[r]; ai[P(8*j + r)] = vi[r]; }
    }
    fft_pass<8> (ar, ai, j, 1.0f);
    fft_pass<64>(ar, ai, j, 1.0f);

    // window in place: Re plane = frame ta, Im plane = frame tb
    #pragma unroll
    for (int r = 0; r < 8; ++r) {
        const int n = j + 64*r;
        const float wd = hann(n) * (1.0f / 512.0f);
        ar[P(n)] *= wd;
        ai[P(n)] *= wd;
    }
    __syncthreads();

    // OLA: outputs i (padded coords) in [t0*128, (t0+8)*128)
    const int ibase = t0 << 7;
    #pragma unroll
    for (int s = tid; s < 1024; s += 384) {
        const int i = ibase + s;
        const int jj = i - PADC;
        if (jj < 0 || jj >= LEN) continue;
        int t_lo = (i >= 384) ? ((i - 384) >> 7) : 0;
        int t_hi = i >> 7; if (t_hi > NT - 1) t_hi = NT - 1;
        float acc = 0.0f;
        if (t_hi - t_lo == 3) {
            #pragma unroll
            for (int u = 0; u < 4; ++u) {
                const int t = t_lo + u;
                const int ft = t - (t0 - 4);
                const int n = i - (t << 7);
                acc += (ft & 1 ? gi : gr)[(ft >> 1) * FBUF + P(n)];
            }
            out[b * LEN + jj] = acc * (2.0f / 3.0f);
        } else {
            float wacc = 0.0f;
            for (int t = t_lo; t <= t_hi; ++t) {
                const int ft = t - (t0 - 4);
                const int n = i - (t << 7);
                const float wd = hann(n);
                acc += (ft & 1 ? gi : gr)[(ft >> 1) * FBUF + P(n)];
                wacc += wd * wd;
            }
            out[b * LEN + jj] = acc / fmaxf(wacc, 1e-11f);
        }
    }
}

extern "C" void kernel_launch(void* const* d_in, const int* in_sizes, int n_in,
                              void* d_out, int out_size, void* d_ws, size_t ws_size,
                              hipStream_t stream) {
    const float* noisy    = (const float*)d_in[0];
    const float* enhanced = (const float*)d_in[1];
    float* out = (float*)d_out;

    // workspace layout (floats), total 20576448 (~82.3 MB):
    //   e_spec : [0, 10288224)              (16*1251*257 float2)
    //   floor  : [10288224, 15432336)
    //   n_mag  : [15432336, 20576448)
    float* ws = (float*)d_ws;
    float2* e_spec = (float2*)ws;
    float* floor_ = ws + 10288224;
    float* n_mag  = ws + 15432336;

    stft_kernel     <<<dim3((NT + 3) / 4, BATCH), dim3(256), 0, stream>>>(enhanced, noisy, e_spec, n_mag);
    floor_kernel    <<<dim3((NT + 15) / 16, BATCH), dim3(256), 0, stream>>>(n_mag, floor_);
    istft_ola_kernel<<<dim3((NT + 7) / 8, BATCH), dim3(384), 0, stream>>>(e_spec, floor_, out);
}

// Round 9
// 145.258 us; speedup vs baseline: 1.0618x; 1.0618x over previous
//
#include <hip/hip_runtime.h>
#include <math.h>

#define BATCH 16
#define LEN   160000
#define NFFT  512
#define HOP   128
#define NT    1251      // 1 + (160000+512-512)/128
#define NF    257
#define PADC  256
#define TWO_PI 6.28318530717958647692f
// padded LDS index: +1 float per 32 -> breaks power-of-2 bank aliasing
#define P(i) ((i) + ((i) >> 5))
#define FBUF 528        // padded 512-float FFT region (P(511)=526 < 528)
#define GSTR 264        // staging row stride: 2 rows == FBUF exactly

__device__ __forceinline__ int reflect_idx(int j) {
    j = j < 0 ? -j : j;
    j = j >= LEN ? 2*LEN - 2 - j : j;
    return j;
}

__device__ __forceinline__ float hann(int n) {
    return 0.5f - 0.5f * __cosf(TWO_PI * (float)n * (1.0f / 512.0f));
}

// ---------- sorted-4-smallest tuple machinery (exact, branchless) ----------
struct T4 { float m0, m1, m2, m3; };   // ascending

__device__ __forceinline__ void ins(T4& a, float v) {
    const float x0 = fminf(a.m0, v);  const float c0 = fmaxf(a.m0, v);
    const float x1 = fminf(a.m1, c0); const float c1 = fmaxf(a.m1, c0);
    const float x2 = fminf(a.m2, c1); const float c2 = fmaxf(a.m2, c1);
    const float x3 = fminf(a.m3, c2);
    a.m0 = x0; a.m1 = x1; a.m2 = x2; a.m3 = x3;
}

__device__ __forceinline__ T4 merge4(const T4& a, const T4& b) {
    const float l0 = fminf(a.m0, b.m3);
    const float l1 = fminf(a.m1, b.m2);
    const float l2 = fminf(a.m2, b.m1);
    const float l3 = fminf(a.m3, b.m0);
    const float t0 = fminf(l0, l2), t2 = fmaxf(l0, l2);
    const float t1 = fminf(l1, l3), t3 = fmaxf(l1, l3);
    T4 r;
    r.m0 = fminf(t0, t1); r.m1 = fmaxf(t0, t1);
    r.m2 = fminf(t2, t3); r.m3 = fmaxf(t2, t3);
    return r;
}

__device__ __forceinline__ T4 sort4(float a, float b, float c, float d) {
    const float x0 = fminf(a, b), x1 = fmaxf(a, b);
    const float x2 = fminf(c, d), x3 = fmaxf(c, d);
    const float y0 = fminf(x0, x2), y2 = fmaxf(x0, x2);
    const float y1 = fminf(x1, x3), y3 = fmaxf(x1, x3);
    T4 r; r.m0 = y0; r.m1 = fminf(y1, y2); r.m2 = fmaxf(y1, y2); r.m3 = y3;
    return r;
}

// 8-point DFT in registers. y[m] = sum_r v[r] * exp(sign*2*pi*i*r*m/8).
__device__ __forceinline__ void dft8(float vr[8], float vi[8], float sign) {
    const float K = 0.70710678118654752f;
    float ar=vr[0]+vr[4], ai=vi[0]+vi[4];
    float br=vr[0]-vr[4], bi=vi[0]-vi[4];
    float cr=vr[2]+vr[6], ci=vi[2]+vi[6];
    float dr=vr[2]-vr[6], di=vi[2]-vi[6];
    float er=vr[1]+vr[5], ei=vi[1]+vi[5];
    float fr=vr[1]-vr[5], fi=vi[1]-vi[5];
    float gr=vr[3]+vr[7], gi=vi[3]+vi[7];
    float hr=vr[3]-vr[7], hi=vi[3]-vi[7];
    const float W4dr = -sign*di, W4di = sign*dr;
    const float W4hr = -sign*hi, W4hi = sign*hr;
    const float E0r=ar+cr, E0i=ai+ci, E2r=ar-cr, E2i=ai-ci;
    const float E1r=br+W4dr, E1i=bi+W4di, E3r=br-W4dr, E3i=bi-W4di;
    const float O0r=er+gr, O0i=ei+gi, O2r=er-gr, O2i=ei-gi;
    const float O1r=fr+W4hr, O1i=fi+W4hi, O3r=fr-W4hr, O3i=fi-W4hi;
    const float T1r = K*(O1r - sign*O1i), T1i = K*(O1i + sign*O1r);
    const float T2r = -sign*O2i,          T2i = sign*O2r;
    const float T3r = K*(-O3r - sign*O3i), T3i = K*(-O3i + sign*O3r);
    vr[0]=E0r+O0r; vi[0]=E0i+O0i;  vr[4]=E0r-O0r; vi[4]=E0i-O0i;
    vr[1]=E1r+T1r; vi[1]=E1i+T1i;  vr[5]=E1r-T1r; vi[5]=E1i-T1i;
    vr[2]=E2r+T2r; vi[2]=E2i+T2i;  vr[6]=E2r-T2r; vi[6]=E2i-T2i;
    vr[3]=E3r+T3r; vi[3]=E3i+T3i;  vr[7]=E3r-T3r; vi[7]=E3i-T3i;
}

// One Stockham radix-8 pass, IN PLACE, one wave = one FFT (j in 0..63).
// Safe without any barrier: all 8 ds_reads precede all 8 ds_writes in
// program order, and DS ops from one wave are processed in order.
template<int NS>
__device__ __forceinline__ void fft_pass(float* R, float* I, int j, float sign) {
    float vr[8], vi[8];
    #pragma unroll
    for (int r = 0; r < 8; ++r) { vr[r] = R[P(j + 64*r)]; vi[r] = I[P(j + 64*r)]; }
    const float th = sign * (TWO_PI / (8.0f * (float)NS)) * (float)(j & (NS - 1));
    float w1r, w1i; __sincosf(th, &w1i, &w1r);
    float wr = w1r, wi = w1i;
    #pragma unroll
    for (int r = 1; r < 8; ++r) {
        const float tr = vr[r]*wr - vi[r]*wi;
        vi[r] = vr[r]*wi + vi[r]*wr; vr[r] = tr;
        const float nwr = wr*w1r - wi*w1i;
        wi = wr*w1i + wi*w1r; wr = nwr;
    }
    dft8(vr, vi, sign);
    const int base = ((j / NS) * (8 * NS)) + (j & (NS - 1));
    #pragma unroll
    for (int r = 0; r < 8; ++r) { R[P(base + r*NS)] = vr[r]; I[P(base + r*NS)] = vi[r]; }
}

// Final pass (NS=64): results stay in REGISTERS. After this, lane j holds
// y[j + 64r] in vr[r]/vi[r] (base = j when NS=64). No LDS write.
__device__ __forceinline__ void fft_pass_last(const float* R, const float* I, int j,
                                              float sign, float vr[8], float vi[8]) {
    #pragma unroll
    for (int r = 0; r < 8; ++r) { vr[r] = R[P(j + 64*r)]; vi[r] = I[P(j + 64*r)]; }
    const float th = sign * (TWO_PI / 512.0f) * (float)j;
    float w1r, w1i; __sincosf(th, &w1i, &w1r);
    float wr = w1r, wi = w1i;
    #pragma unroll
    for (int r = 1; r < 8; ++r) {
        const float tr = vr[r]*wr - vi[r]*wi;
        vi[r] = vr[r]*wi + vi[r]*wr; vr[r] = tr;
        const float nwr = wr*w1r - wi*w1i;
        wi = wr*w1i + wi*w1r; wr = nwr;
    }
    dft8(vr, vi, sign);
}

// K1: STFT of BOTH signals via one complex FFT per frame: z = enh + i*noi.
// 4 frames per block (one per wave), wave-autonomous in-place radix-8
// Stockham, ZERO __syncthreads. Last pass in registers; Hermitian
// extraction via __shfl (partner Z[512-kk] = lane (64-j)&63, reg 7-r).
__global__ __launch_bounds__(256, 4) void stft_kernel(const float* __restrict__ enh,
                                                      const float* __restrict__ noi,
                                                      float2* __restrict__ e_spec,
                                                      float*  __restrict__ n_mag) {
    __shared__ float Ar[4*FBUF], Ai[4*FBUF];
    const int tid = threadIdx.x;
    const int w = tid >> 6, j = tid & 63;
    const int tr_ = blockIdx.x * 4 + w;
    const bool live = tr_ < NT;
    const int t = live ? tr_ : NT - 1;
    const int b = blockIdx.y;
    float* ar = Ar + w*FBUF; float* ai = Ai + w*FBUF;

    // pass 0: global -> registers (windowed), dft8, write A
    {
        const int sbase = t * HOP - PADC;
        float vr[8], vi[8];
        if (sbase >= 0 && sbase + NFFT <= LEN) {
            // interior fast path: no reflect, direct coalesced loads
            const float* __restrict__ pe = enh + b * LEN + sbase;
            const float* __restrict__ pn = noi + b * LEN + sbase;
            #pragma unroll
            for (int r = 0; r < 8; ++r) {
                const int n = j + 64*r;
                const float wd = hann(n);
                vr[r] = pe[n] * wd;
                vi[r] = pn[n] * wd;
            }
        } else {
            const float* __restrict__ pe = enh + b * LEN;
            const float* __restrict__ pn = noi + b * LEN;
            #pragma unroll
            for (int r = 0; r < 8; ++r) {
                const int n = j + 64*r;
                const int idx = reflect_idx(sbase + n);
                const float wd = hann(n);
                vr[r] = pe[idx] * wd;
                vi[r] = pn[idx] * wd;
            }
        }
        dft8(vr, vi, -1.0f);
        #pragma unroll
        for (int r = 0; r < 8; ++r) { ar[P(8*j + r)] = vr[r]; ai[P(8*j + r)] = vi[r]; }
    }
    fft_pass<8>(ar, ai, j, -1.0f);
    float zr[8], zi[8];
    fft_pass_last(ar, ai, j, -1.0f, zr, zi);

    // Hermitian partner via cross-lane shuffle (regs 4..7 of lane (64-j)&63)
    const int src = (64 - j) & 63;
    float pr[4], pi_[4];
    #pragma unroll
    for (int q = 4; q < 8; ++q) {
        pr[q-4]  = __shfl(zr[q], src);
        pi_[q-4] = __shfl(zi[q], src);
    }
    if (live) {
        const int obase = (b * NT + t) * NF;
        #pragma unroll
        for (int r = 0; r < 4; ++r) {
            const int kk = j + 64*r;
            // lane 0's partner is its own reg (8-r)&7; others: shuffled reg 7-r
            const float yr = (j == 0) ? zr[(8 - r) & 7] : pr[3 - r];
            const float yi = (j == 0) ? zi[(8 - r) & 7] : pi_[3 - r];
            const float er = 0.5f*(zr[r] + yr), ei = 0.5f*(zi[r] - yi);
            const float nr = 0.5f*(zi[r] + yi), ni = 0.5f*(yr - zr[r]);
            e_spec[obase + kk] = make_float2(er, ei);
            n_mag[obase + kk] = fmaxf(sqrtf(nr*nr + ni*ni), 1e-6f);
        }
        if (j == 0) {   // kk = 256: self-conjugate bin
            e_spec[obase + 256] = make_float2(zr[4], 0.0f);
            n_mag[obase + 256] = fmaxf(fabsf(zi[4]), 1e-6f);
        }
    }
}

// K2: FULLY fused floor. Tile = 16 outputs (24 quantile rows incl. +/-4
// halo; 54-element time window in registers). Quantile = 4th-smallest of
// 31 via chunked selection. Freq-pool k=5 via LDS; time-pool k=9 sliding.
__global__ __launch_bounds__(256) void floor_kernel(const float* __restrict__ n_mag,
                                                    float* __restrict__ floor_) {
    __shared__ float q[24][GSTR];
    __shared__ float fq[24];
    const int tid = threadIdx.x;
    const int t0 = blockIdx.x * 16, b = blockIdx.y;
    const float* __restrict__ pb = n_mag + b * NT * NF;

    // ---- phase A: quantile rows k=0..23 (tq = t0-4+k) for f = tid ----
    {
        float wv[54];
        #pragma unroll
        for (int r = 0; r < 54; ++r) {
            int tr = t0 - 19 + r;
            tr = tr < 0 ? 0 : (tr > NT - 1 ? NT - 1 : tr);
            wv[r] = pb[tr * NF + tid];
        }
        T4 ch[6];
        #pragma unroll
        for (int c = 0; c < 6; ++c)
            ch[c] = merge4(sort4(wv[8*c],   wv[8*c+1], wv[8*c+2], wv[8*c+3]),
                           sort4(wv[8*c+4], wv[8*c+5], wv[8*c+6], wv[8*c+7]));
        #pragma unroll
        for (int k = 0; k < 24; ++k) {
            const int c0 = (k + 7) >> 3;      // full chunks c0, c0+1, c0+2
            T4 m = merge4(merge4(ch[c0], ch[c0+1]), ch[c0+2]);
            #pragma unroll
            for (int jj = k; jj < 8*c0; ++jj) ins(m, wv[jj]);        // head
            #pragma unroll
            for (int jj = 8*c0 + 24; jj < k + 31; ++jj) ins(m, wv[jj]); // tail
            q[k][tid] = m.m3;
        }
    }
    // f = 256 column: threads 0..23, one quantile row each (naive 31-insert)
    if (tid < 24) {
        const int k = tid;
        T4 m; m.m0 = m.m1 = m.m2 = m.m3 = 3.4e38f;
        for (int dt = -15; dt <= 15; ++dt) {
            int tt = t0 - 4 + k + dt;
            tt = tt < 0 ? 0 : (tt > NT - 1 ? NT - 1 : tt);
            ins(m, pb[tt * NF + 256]);
        }
        q[k][256] = m.m3;
    }
    __syncthreads();

    // ---- phase B: freq pool k=5 (zero-pad) into registers ----
    float fp[24];
    {
        const int f = tid;
        #pragma unroll
        for (int k = 0; k < 24; ++k) {
            float acc = 0.0f;
            #pragma unroll
            for (int df = -2; df <= 2; ++df) {
                const int ff = f + df;
                if (ff >= 0 && ff < NF) acc += q[k][ff];
            }
            fp[k] = acc * (1.0f / 5.0f);
        }
    }
    if (tid < 24) {   // f = 256 pooled rows -> fq
        const int k = tid;
        fq[k] = (q[k][254] + q[k][255] + q[k][256]) * (1.0f / 5.0f);
    }
    __syncthreads();

    // ---- phase C: zero out-of-range rows, time pool k=9 sliding, store ----
    {
        const int f = tid;
        #pragma unroll
        for (int k = 0; k < 24; ++k) {
            const int tq = t0 - 4 + k;
            fp[k] = (tq >= 0 && tq < NT) ? fp[k] : 0.0f;
        }
        float acc = 0.0f;
        #pragma unroll
        for (int k = 0; k < 9; ++k) acc += fp[k];
        #pragma unroll
        for (int to = 0; to < 16; ++to) {
            const int t = t0 + to;
            if (t < NT)
                floor_[(b * NT + t) * NF + f] = fmaxf(acc * (1.0f / 9.0f), 1e-6f);
            if (to < 15) acc += fp[to + 9] - fp[to];
        }
    }
    if (tid < 16) {   // f = 256 outputs
        const int to = tid;
        const int t = t0 + to;
        if (t < NT) {
            float acc = 0.0f;
            #pragma unroll
            for (int k = 0; k < 9; ++k) {
                const int tq = t0 - 4 + to + k;
                acc += (tq >= 0 && tq < NT) ? fq[to + k] : 0.0f;
            }
            floor_[(b * NT + t) * NF + 256] = fmaxf(acc * (1.0f / 9.0f), 1e-6f);
        }
    }
}

// K3: fused [sigmoid mask + apply] + ISTFT. 8 frames per block; each wave
// handles 2 frames independently (packed IFFT). Last pass in registers ->
// frames written straight from regs. ZERO __syncthreads.
__global__ __launch_bounds__(256, 4) void istft_kernel(const float2* __restrict__ g,
                                                       const float* __restrict__ floor_,
                                                       float* __restrict__ frames) {
    __shared__ float gr[8*GSTR], gi[8*GSTR];
    const int tid = threadIdx.x;
    const int w = tid >> 6, j = tid & 63;
    const int t0 = blockIdx.x * 8, b = blockIdx.y;
    const int ta = t0 + 2*w, tb = ta + 1;

    float* g0r = gr + (2*w) * GSTR;      float* g0i = gi + (2*w) * GSTR;
    float* g1r = gr + (2*w + 1) * GSTR;  float* g1i = gi + (2*w + 1) * GSTR;

    // mask phase (wave-local): fill this wave's 2 staging rows
    for (int e = j; e < 2 * NF; e += 64) {
        const int h = (e >= NF) ? 1 : 0;
        const int kk = e - h * NF;
        const int t = ta + h;
        float grv = 0.0f, giv = 0.0f;
        if (t < NT) {
            const int idx = (b * NT + t) * NF + kk;
            const float fl = floor_[idx];
            const float2 e2 = g[idx];
            const float a = sqrtf(e2.x * e2.x + e2.y * e2.y);
            const float emag = fmaxf(a, 1e-6f);
            const float xarg = (emag - 1.5f * fl) / (0.15f * fl + 1e-6f);
            const float mask = 1.0f / (1.0f + __expf(-xarg));
            const float fm = 0.08f + 0.92f * (0.65f + 0.35f * mask);
            const float scale = emag * fm / fmaxf(a, 1e-12f);
            grv = e2.x * scale; giv = e2.y * scale;
        }
        gr[(2*w + h) * GSTR + kk] = grv;
        gi[(2*w + h) * GSTR + kk] = giv;
    }

    float* ar = g0r;   // FFT region = this wave's two staging rows (528 floats)
    float* ai = g0i;

    // pass 0: build packed C(n) = G1full + i*G2full from staging, dft8,
    // write back into the same region (all reads precede all writes).
    {
        float vr[8], vi[8];
        #pragma unroll
        for (int r = 0; r < 8; ++r) {
            const int n = j + 64*r;
            float cr, ci;
            if (n <= 256) {
                cr = g0r[n] - g1i[n];
                ci = g0i[n] + g1r[n];
            } else {
                const int m = 512 - n;
                cr = g0r[m] + g1i[m];
                ci = g1r[m] - g0i[m];
            }
            vr[r] = cr; vi[r] = ci;
        }
        dft8(vr, vi, 1.0f);
        #pragma unroll
        for (int r = 0; r < 8; ++r) { ar[P(8*j + r)] = vr[r]; ai[P(8*j + r)] = vi[r]; }
    }
    fft_pass<8>(ar, ai, j, 1.0f);
    float xr[8], xi[8];
    fft_pass_last(ar, ai, j, 1.0f, xr, xi);

    // x1(n) = Re -> frame ta, x2(n) = Im -> frame tb, straight from regs
    #pragma unroll
    for (int r = 0; r < 8; ++r) {
        const int n = j + 64*r;
        const float wd = hann(n) * (1.0f / 512.0f);
        if (ta < NT) frames[(b * NT + ta) * NFFT + n] = xr[r] * wd;
        if (tb < NT) frames[(b * NT + tb) * NFFT + n] = xi[r] * wd;
    }
}

// K4: overlap-add, vectorized x4. An aligned float4 never crosses a hop
// boundary (n0 <= 124), so t_lo/t_hi are uniform per quad. Interior
// (4 frames): sum(hann^2 at hop 128) == 1.5 exactly.
__global__ __launch_bounds__(256) void ola_kernel(const float* __restrict__ frames,
                                                  float* __restrict__ out) {
    const int gid = blockIdx.x * 256 + threadIdx.x;
    if (gid >= BATCH * (LEN / 4)) return;
    const int b = gid / (LEN / 4);
    const int jj = (gid - b * (LEN / 4)) * 4;
    const int i = jj + PADC;
    const int q = i >> 7;
    const int n0 = i & 127;
    if (q >= 3 && q <= NT - 1) {
        // frames q-u at tap n0+128u -> fp - 384u
        const float* __restrict__ fp = frames + (b * NT + q) * NFFT + n0;
        const float4 a0 = *(const float4*)(fp);
        const float4 a1 = *(const float4*)(fp - 384);
        const float4 a2 = *(const float4*)(fp - 768);
        const float4 a3 = *(const float4*)(fp - 1152);
        float4 o;
        o.x = (a0.x + a1.x + a2.x + a3.x) * (2.0f / 3.0f);
        o.y = (a0.y + a1.y + a2.y + a3.y) * (2.0f / 3.0f);
        o.z = (a0.z + a1.z + a2.z + a3.z) * (2.0f / 3.0f);
        o.w = (a0.w + a1.w + a2.w + a3.w) * (2.0f / 3.0f);
        *(float4*)(out + b * LEN + jj) = o;
    } else {
        #pragma unroll
        for (int e = 0; e < 4; ++e) {
            const int ie = i + e;
            int t_lo = (ie >= 384) ? ((ie - 384) >> 7) : 0;
            int t_hi = ie >> 7; if (t_hi > NT - 1) t_hi = NT - 1;
            float acc = 0.0f, wacc = 0.0f;
            for (int t = t_lo; t <= t_hi; ++t) {
                const int n = ie - (t << 7);
                const float wd = hann(n);
                acc  += frames[(b * NT + t) * NFFT + n];
                wacc += wd * wd;
            }
            out[b * LEN + jj + e] = acc / fmaxf(wacc, 1e-11f);
        }
    }
}

extern "C" void kernel_launch(void* const* d_in, const int* in_sizes, int n_in,
                              void* d_out, int out_size, void* d_ws, size_t ws_size,
                              hipStream_t stream) {
    const float* noisy    = (const float*)d_in[0];
    const float* enhanced = (const float*)d_in[1];
    float* out = (float*)d_out;

    // workspace layout (floats), total 25680528 (~102.7 MB):
    //   e_spec : [0, 10288224)              (16*1251*257 float2)
    //   floor  : [10288224, 15432336)
    //   n_mag  : [15432336, 20576448)       (dead after floor_kernel)
    //   frames : [15432336, 25680528)       (reuses dead n_mag region)
    float* ws = (float*)d_ws;
    float2* e_spec = (float2*)ws;
    float* floor_ = ws + 10288224;
    float* n_mag  = ws + 15432336;
    float* frames = ws + 15432336;

    stft_kernel <<<dim3((NT + 3) / 4, BATCH), dim3(256), 0, stream>>>(enhanced, noisy, e_spec, n_mag);
    floor_kernel<<<dim3((NT + 15) / 16, BATCH), dim3(256), 0, stream>>>(n_mag, floor_);
    istft_kernel<<<dim3((NT + 7) / 8, BATCH), dim3(256), 0, stream>>>(e_spec, floor_, frames);
    ola_kernel  <<<dim3((BATCH * (LEN / 4) + 255) / 256), dim3(256), 0, stream>>>(frames, out);
}

// Round 10
// 142.683 us; speedup vs baseline: 1.0810x; 1.0180x over previous
//
#include <hip/hip_runtime.h>
#include <math.h>

#define BATCH 16
#define LEN   160000
#define NFFT  512
#define HOP   128
#define NT    1251      // 1 + (160000+512-512)/128
#define NF    257
#define PADC  256
#define TWO_PI 6.28318530717958647692f
// padded LDS index: +1 float per 32 -> breaks power-of-2 bank aliasing
#define P(i) ((i) + ((i) >> 5))
#define FBUF 528        // padded 512-float FFT region (P(511)=526 < 528)
#define GSTR 264        // staging row stride: 2 rows == FBUF exactly

__device__ __forceinline__ int reflect_idx(int j) {
    j = j < 0 ? -j : j;
    j = j >= LEN ? 2*LEN - 2 - j : j;
    return j;
}

__device__ __forceinline__ float hann(int n) {
    return 0.5f - 0.5f * __cosf(TWO_PI * (float)n * (1.0f / 512.0f));
}

// ---------- sorted-4-smallest tuple machinery (exact, branchless) ----------
struct T4 { float m0, m1, m2, m3; };   // ascending

__device__ __forceinline__ void ins(T4& a, float v) {
    const float x0 = fminf(a.m0, v);  const float c0 = fmaxf(a.m0, v);
    const float x1 = fminf(a.m1, c0); const float c1 = fmaxf(a.m1, c0);
    const float x2 = fminf(a.m2, c1); const float c2 = fmaxf(a.m2, c1);
    const float x3 = fminf(a.m3, c2);
    a.m0 = x0; a.m1 = x1; a.m2 = x2; a.m3 = x3;
}

__device__ __forceinline__ T4 merge4(const T4& a, const T4& b) {
    const float l0 = fminf(a.m0, b.m3);
    const float l1 = fminf(a.m1, b.m2);
    const float l2 = fminf(a.m2, b.m1);
    const float l3 = fminf(a.m3, b.m0);
    const float t0 = fminf(l0, l2), t2 = fmaxf(l0, l2);
    const float t1 = fminf(l1, l3), t3 = fmaxf(l1, l3);
    T4 r;
    r.m0 = fminf(t0, t1); r.m1 = fmaxf(t0, t1);
    r.m2 = fminf(t2, t3); r.m3 = fmaxf(t2, t3);
    return r;
}

__device__ __forceinline__ T4 sort4(float a, float b, float c, float d) {
    const float x0 = fminf(a, b), x1 = fmaxf(a, b);
    const float x2 = fminf(c, d), x3 = fmaxf(c, d);
    const float y0 = fminf(x0, x2), y2 = fmaxf(x0, x2);
    const float y1 = fminf(x1, x3), y3 = fmaxf(x1, x3);
    T4 r; r.m0 = y0; r.m1 = fminf(y1, y2); r.m2 = fmaxf(y1, y2); r.m3 = y3;
    return r;
}

// 8-point DFT in registers. y[m] = sum_r v[r] * exp(sign*2*pi*i*r*m/8).
__device__ __forceinline__ void dft8(float vr[8], float vi[8], float sign) {
    const float K = 0.70710678118654752f;
    float ar=vr[0]+vr[4], ai=vi[0]+vi[4];
    float br=vr[0]-vr[4], bi=vi[0]-vi[4];
    float cr=vr[2]+vr[6], ci=vi[2]+vi[6];
    float dr=vr[2]-vr[6], di=vi[2]-vi[6];
    float er=vr[1]+vr[5], ei=vi[1]+vi[5];
    float fr=vr[1]-vr[5], fi=vi[1]-vi[5];
    float gr=vr[3]+vr[7], gi=vi[3]+vi[7];
    float hr=vr[3]-vr[7], hi=vi[3]-vi[7];
    const float W4dr = -sign*di, W4di = sign*dr;
    const float W4hr = -sign*hi, W4hi = sign*hr;
    const float E0r=ar+cr, E0i=ai+ci, E2r=ar-cr, E2i=ai-ci;
    const float E1r=br+W4dr, E1i=bi+W4di, E3r=br-W4dr, E3i=bi-W4di;
    const float O0r=er+gr, O0i=ei+gi, O2r=er-gr, O2i=ei-gi;
    const float O1r=fr+W4hr, O1i=fi+W4hi, O3r=fr-W4hr, O3i=fi-W4hi;
    const float T1r = K*(O1r - sign*O1i), T1i = K*(O1i + sign*O1r);
    const float T2r = -sign*O2i,          T2i = sign*O2r;
    const float T3r = K*(-O3r - sign*O3i), T3i = K*(-O3i + sign*O3r);
    vr[0]=E0r+O0r; vi[0]=E0i+O0i;  vr[4]=E0r-O0r; vi[4]=E0i-O0i;
    vr[1]=E1r+T1r; vi[1]=E1i+T1i;  vr[5]=E1r-T1r; vi[5]=E1i-T1i;
    vr[2]=E2r+T2r; vi[2]=E2i+T2i;  vr[6]=E2r-T2r; vi[6]=E2i-T2i;
    vr[3]=E3r+T3r; vi[3]=E3i+T3i;  vr[7]=E3r-T3r; vi[7]=E3i-T3i;
}

// One Stockham radix-8 pass, IN PLACE, one wave = one FFT (j in 0..63).
// Safe without any barrier: all 8 ds_reads precede all 8 ds_writes in
// program order, and DS ops from one wave are processed in order.
template<int NS>
__device__ __forceinline__ void fft_pass(float* R, float* I, int j, float sign) {
    float vr[8], vi[8];
    #pragma unroll
    for (int r = 0; r < 8; ++r) { vr[r] = R[P(j + 64*r)]; vi[r] = I[P(j + 64*r)]; }
    const float th = sign * (TWO_PI / (8.0f * (float)NS)) * (float)(j & (NS - 1));
    float w1r, w1i; __sincosf(th, &w1i, &w1r);
    float wr = w1r, wi = w1i;
    #pragma unroll
    for (int r = 1; r < 8; ++r) {
        const float tr = vr[r]*wr - vi[r]*wi;
        vi[r] = vr[r]*wi + vi[r]*wr; vr[r] = tr;
        const float nwr = wr*w1r - wi*w1i;
        wi = wr*w1i + wi*w1r; wr = nwr;
    }
    dft8(vr, vi, sign);
    const int base = ((j / NS) * (8 * NS)) + (j & (NS - 1));
    #pragma unroll
    for (int r = 0; r < 8; ++r) { R[P(base + r*NS)] = vr[r]; I[P(base + r*NS)] = vi[r]; }
}

// Final pass (NS=64): results stay in REGISTERS. After this, lane j holds
// y[j + 64r] in vr[r]/vi[r] (base = j when NS=64). No LDS write.
__device__ __forceinline__ void fft_pass_last(const float* R, const float* I, int j,
                                              float sign, float vr[8], float vi[8]) {
    #pragma unroll
    for (int r = 0; r < 8; ++r) { vr[r] = R[P(j + 64*r)]; vi[r] = I[P(j + 64*r)]; }
    const float th = sign * (TWO_PI / 512.0f) * (float)j;
    float w1r, w1i; __sincosf(th, &w1i, &w1r);
    float wr = w1r, wi = w1i;
    #pragma unroll
    for (int r = 1; r < 8; ++r) {
        const float tr = vr[r]*wr - vi[r]*wi;
        vi[r] = vr[r]*wi + vi[r]*wr; vr[r] = tr;
        const float nwr = wr*w1r - wi*w1i;
        wi = wr*w1i + wi*w1r; wr = nwr;
    }
    dft8(vr, vi, sign);
}

// K1: STFT of BOTH signals via one complex FFT per frame: z = enh + i*noi.
// 4 frames per block (one per wave), wave-autonomous in-place radix-8
// Stockham, ZERO __syncthreads. Last pass in registers; Hermitian
// extraction via __shfl (partner Z[512-kk] = lane (64-j)&63, reg 7-r).
__global__ __launch_bounds__(256, 4) void stft_kernel(const float* __restrict__ enh,
                                                      const float* __restrict__ noi,
                                                      float2* __restrict__ e_spec,
                                                      float*  __restrict__ n_mag) {
    __shared__ float Ar[4*FBUF], Ai[4*FBUF];
    const int tid = threadIdx.x;
    const int w = tid >> 6, j = tid & 63;
    const int tr_ = blockIdx.x * 4 + w;
    const bool live = tr_ < NT;
    const int t = live ? tr_ : NT - 1;
    const int b = blockIdx.y;
    float* ar = Ar + w*FBUF; float* ai = Ai + w*FBUF;

    // pass 0: global -> registers (windowed), dft8, write A
    {
        const int sbase = t * HOP - PADC;
        float vr[8], vi[8];
        if (sbase >= 0 && sbase + NFFT <= LEN) {
            const float* __restrict__ pe = enh + b * LEN + sbase;
            const float* __restrict__ pn = noi + b * LEN + sbase;
            #pragma unroll
            for (int r = 0; r < 8; ++r) {
                const int n = j + 64*r;
                const float wd = hann(n);
                vr[r] = pe[n] * wd;
                vi[r] = pn[n] * wd;
            }
        } else {
            const float* __restrict__ pe = enh + b * LEN;
            const float* __restrict__ pn = noi + b * LEN;
            #pragma unroll
            for (int r = 0; r < 8; ++r) {
                const int n = j + 64*r;
                const int idx = reflect_idx(sbase + n);
                const float wd = hann(n);
                vr[r] = pe[idx] * wd;
                vi[r] = pn[idx] * wd;
            }
        }
        dft8(vr, vi, -1.0f);
        #pragma unroll
        for (int r = 0; r < 8; ++r) { ar[P(8*j + r)] = vr[r]; ai[P(8*j + r)] = vi[r]; }
    }
    fft_pass<8>(ar, ai, j, -1.0f);
    float zr[8], zi[8];
    fft_pass_last(ar, ai, j, -1.0f, zr, zi);

    // Hermitian partner via cross-lane shuffle (regs 4..7 of lane (64-j)&63)
    const int src = (64 - j) & 63;
    float pr[4], pi_[4];
    #pragma unroll
    for (int q = 4; q < 8; ++q) {
        pr[q-4]  = __shfl(zr[q], src);
        pi_[q-4] = __shfl(zi[q], src);
    }
    if (live) {
        const int obase = (b * NT + t) * NF;
        #pragma unroll
        for (int r = 0; r < 4; ++r) {
            const int kk = j + 64*r;
            const float yr = (j == 0) ? zr[(8 - r) & 7] : pr[3 - r];
            const float yi = (j == 0) ? zi[(8 - r) & 7] : pi_[3 - r];
            const float er = 0.5f*(zr[r] + yr), ei = 0.5f*(zi[r] - yi);
            const float nr = 0.5f*(zi[r] + yi), ni = 0.5f*(yr - zr[r]);
            e_spec[obase + kk] = make_float2(er, ei);
            n_mag[obase + kk] = fmaxf(sqrtf(nr*nr + ni*ni), 1e-6f);
        }
        if (j == 0) {   // kk = 256: self-conjugate bin
            e_spec[obase + 256] = make_float2(zr[4], 0.0f);
            n_mag[obase + 256] = fmaxf(fabsf(zi[4]), 1e-6f);
        }
    }
}

// K2: FULLY fused floor. Tile = 16 outputs (24 quantile rows incl. +/-4
// halo; 54-element time window in registers). Quantile = 4th-smallest of
// 31 via chunked selection. Freq-pool k=5 via LDS; time-pool k=9 sliding.
__global__ __launch_bounds__(256) void floor_kernel(const float* __restrict__ n_mag,
                                                    float* __restrict__ floor_) {
    __shared__ float q[24][GSTR];
    __shared__ float fq[24];
    const int tid = threadIdx.x;
    const int t0 = blockIdx.x * 16, b = blockIdx.y;
    const float* __restrict__ pb = n_mag + b * NT * NF;

    // ---- phase A: quantile rows k=0..23 (tq = t0-4+k) for f = tid ----
    {
        float wv[54];
        #pragma unroll
        for (int r = 0; r < 54; ++r) {
            int tr = t0 - 19 + r;
            tr = tr < 0 ? 0 : (tr > NT - 1 ? NT - 1 : tr);
            wv[r] = pb[tr * NF + tid];
        }
        T4 ch[6];
        #pragma unroll
        for (int c = 0; c < 6; ++c)
            ch[c] = merge4(sort4(wv[8*c],   wv[8*c+1], wv[8*c+2], wv[8*c+3]),
                           sort4(wv[8*c+4], wv[8*c+5], wv[8*c+6], wv[8*c+7]));
        #pragma unroll
        for (int k = 0; k < 24; ++k) {
            const int c0 = (k + 7) >> 3;      // full chunks c0, c0+1, c0+2
            T4 m = merge4(merge4(ch[c0], ch[c0+1]), ch[c0+2]);
            #pragma unroll
            for (int jj = k; jj < 8*c0; ++jj) ins(m, wv[jj]);        // head
            #pragma unroll
            for (int jj = 8*c0 + 24; jj < k + 31; ++jj) ins(m, wv[jj]); // tail
            q[k][tid] = m.m3;
        }
    }
    // f = 256 column: threads 0..23, one quantile row each (naive 31-insert)
    if (tid < 24) {
        const int k = tid;
        T4 m; m.m0 = m.m1 = m.m2 = m.m3 = 3.4e38f;
        for (int dt = -15; dt <= 15; ++dt) {
            int tt = t0 - 4 + k + dt;
            tt = tt < 0 ? 0 : (tt > NT - 1 ? NT - 1 : tt);
            ins(m, pb[tt * NF + 256]);
        }
        q[k][256] = m.m3;
    }
    __syncthreads();

    // ---- phase B: freq pool k=5 (zero-pad) into registers ----
    float fp[24];
    {
        const int f = tid;
        #pragma unroll
        for (int k = 0; k < 24; ++k) {
            float acc = 0.0f;
            #pragma unroll
            for (int df = -2; df <= 2; ++df) {
                const int ff = f + df;
                if (ff >= 0 && ff < NF) acc += q[k][ff];
            }
            fp[k] = acc * (1.0f / 5.0f);
        }
    }
    if (tid < 24) {   // f = 256 pooled rows -> fq
        const int k = tid;
        fq[k] = (q[k][254] + q[k][255] + q[k][256]) * (1.0f / 5.0f);
    }
    __syncthreads();

    // ---- phase C: zero out-of-range rows, time pool k=9 sliding, store ----
    {
        const int f = tid;
        #pragma unroll
        for (int k = 0; k < 24; ++k) {
            const int tq = t0 - 4 + k;
            fp[k] = (tq >= 0 && tq < NT) ? fp[k] : 0.0f;
        }
        float acc = 0.0f;
        #pragma unroll
        for (int k = 0; k < 9; ++k) acc += fp[k];
        #pragma unroll
        for (int to = 0; to < 16; ++to) {
            const int t = t0 + to;
            if (t < NT)
                floor_[(b * NT + t) * NF + f] = fmaxf(acc * (1.0f / 9.0f), 1e-6f);
            if (to < 15) acc += fp[to + 9] - fp[to];
        }
    }
    if (tid < 16) {   // f = 256 outputs
        const int to = tid;
        const int t = t0 + to;
        if (t < NT) {
            float acc = 0.0f;
            #pragma unroll
            for (int k = 0; k < 9; ++k) {
                const int tq = t0 - 4 + to + k;
                acc += (tq >= 0 && tq < NT) ? fq[to + k] : 0.0f;
            }
            floor_[(b * NT + t) * NF + 256] = fmaxf(acc * (1.0f / 9.0f), 1e-6f);
        }
    }
}

// K3: fused [mask + ISTFT + OLA]. Block = 256 threads / 4 waves computes
// frames t0..t0+7 EXACTLY ONCE (wave-local packed IFFTs, zero halo),
// windows them into LDS, one barrier, then overlap-adds:
//   - samples fully covered by this block's frames -> plain store
//   - block-boundary samples -> atomicAdd of the pre-normalized partial
// (out is zeroed by hipMemsetAsync; wacc is analytic so partials are
// order-independent). Replaces istft + ola and the 82 MB frames buffer.
__global__ __launch_bounds__(256, 4) void istft_ola_kernel(const float2* __restrict__ g,
                                                           const float* __restrict__ floor_,
                                                           float* __restrict__ out) {
    __shared__ float gr[8*GSTR], gi[8*GSTR];
    const int tid = threadIdx.x;
    const int w = tid >> 6, j = tid & 63;
    const int t0 = blockIdx.x * 8, b = blockIdx.y;
    const int ta = t0 + 2*w, tb = ta + 1;

    float* g0r = gr + (2*w) * GSTR;      float* g0i = gi + (2*w) * GSTR;
    float* g1r = gr + (2*w + 1) * GSTR;  float* g1i = gi + (2*w + 1) * GSTR;

    // mask phase (wave-local): fill this wave's 2 staging rows
    for (int e = j; e < 2 * NF; e += 64) {
        const int h = (e >= NF) ? 1 : 0;
        const int kk = e - h * NF;
        const int t = ta + h;
        float grv = 0.0f, giv = 0.0f;
        if (t < NT) {
            const int idx = (b * NT + t) * NF + kk;
            const float fl = floor_[idx];
            const float2 e2 = g[idx];
            const float a = sqrtf(e2.x * e2.x + e2.y * e2.y);
            const float emag = fmaxf(a, 1e-6f);
            const float xarg = (emag - 1.5f * fl) / (0.15f * fl + 1e-6f);
            const float mask = 1.0f / (1.0f + __expf(-xarg));
            const float fm = 0.08f + 0.92f * (0.65f + 0.35f * mask);
            const float scale = emag * fm / fmaxf(a, 1e-12f);
            grv = e2.x * scale; giv = e2.y * scale;
        }
        gr[(2*w + h) * GSTR + kk] = grv;
        gi[(2*w + h) * GSTR + kk] = giv;
    }

    float* ar = g0r;   // FFT region = this wave's two staging rows (528 floats)
    float* ai = g0i;

    // pass 0: build packed C(n) = G1full + i*G2full from staging, dft8,
    // write back into the same region (all reads precede all writes).
    {
        float vr[8], vi[8];
        #pragma unroll
        for (int r = 0; r < 8; ++r) {
            const int n = j + 64*r;
            float cr, ci;
            if (n <= 256) {
                cr = g0r[n] - g1i[n];
                ci = g0i[n] + g1r[n];
            } else {
                const int m = 512 - n;
                cr = g0r[m] + g1i[m];
                ci = g1r[m] - g0i[m];
            }
            vr[r] = cr; vi[r] = ci;
        }
        dft8(vr, vi, 1.0f);
        #pragma unroll
        for (int r = 0; r < 8; ++r) { ar[P(8*j + r)] = vr[r]; ai[P(8*j + r)] = vi[r]; }
    }
    fft_pass<8>(ar, ai, j, 1.0f);
    float xr[8], xi[8];
    fft_pass_last(ar, ai, j, 1.0f, xr, xi);

    // window in place: Re plane = frame ta, Im plane = frame tb
    #pragma unroll
    for (int r = 0; r < 8; ++r) {
        const int n = j + 64*r;
        const float wd = hann(n) * (1.0f / 512.0f);
        ar[P(n)] = xr[r] * wd;
        ai[P(n)] = xi[r] * wd;
    }
    __syncthreads();

    // OLA: samples i in [t0*128, t0*128 + 1408) (padded coords)
    const int i0 = t0 << 7;
    for (int s = tid; s < 1408; s += 256) {
        const int i = i0 + s;
        const int jj = i - PADC;
        if (jj < 0 || jj >= LEN) continue;
        const int tl = (i >= 384) ? ((i - 384) >> 7) : 0;
        int th = i >> 7; if (th > NT - 1) th = NT - 1;
        const int ca = tl > t0 ? tl : t0;             // this block's frame range
        const int cb = th < t0 + 7 ? th : t0 + 7;
        if (cb < ca) continue;
        float acc = 0.0f;
        for (int t = ca; t <= cb; ++t) {
            const int ft = t - t0;
            const int n = i - (t << 7);
            acc += ((ft & 1) ? gi : gr)[(ft >> 1) * FBUF + P(n)];
        }
        float winv;
        if (th - tl == 3) winv = (2.0f / 3.0f);       // COLA: sum hann^2 = 1.5
        else {
            float wacc = 0.0f;
            for (int t = tl; t <= th; ++t) {
                const float wd = hann(i - (t << 7));
                wacc += wd * wd;
            }
            winv = 1.0f / fmaxf(wacc, 1e-11f);
        }
        const float v = acc * winv;
        if (tl >= t0 && th <= t0 + 7) out[b * LEN + jj] = v;        // unique owner
        else atomicAdd(out + b * LEN + jj, v);                      // boundary partial
    }
}

extern "C" void kernel_launch(void* const* d_in, const int* in_sizes, int n_in,
                              void* d_out, int out_size, void* d_ws, size_t ws_size,
                              hipStream_t stream) {
    const float* noisy    = (const float*)d_in[0];
    const float* enhanced = (const float*)d_in[1];
    float* out = (float*)d_out;

    // workspace layout (floats), total 20576448 (~82.3 MB):
    //   e_spec : [0, 10288224)              (16*1251*257 float2)
    //   floor  : [10288224, 15432336)
    //   n_mag  : [15432336, 20576448)
    float* ws = (float*)d_ws;
    float2* e_spec = (float2*)ws;
    float* floor_ = ws + 10288224;
    float* n_mag  = ws + 15432336;

    stft_kernel <<<dim3((NT + 3) / 4, BATCH), dim3(256), 0, stream>>>(enhanced, noisy, e_spec, n_mag);
    floor_kernel<<<dim3((NT + 15) / 16, BATCH), dim3(256), 0, stream>>>(n_mag, floor_);
    hipMemsetAsync(out, 0, (size_t)BATCH * LEN * sizeof(float), stream);
    istft_ola_kernel<<<dim3((NT + 7) / 8, BATCH), dim3(256), 0, stream>>>(e_spec, floor_, out);
}